// Round 6
// baseline (785.266 us; speedup 1.0000x reference)
//
#include <hip/hip_runtime.h>
#include <hip/hip_bf16.h>

typedef __bf16 bf16_t;
typedef __bf16 bf16x2 __attribute__((ext_vector_type(2)));
typedef __bf16 bf16x4 __attribute__((ext_vector_type(4)));
typedef __bf16 bf16x8 __attribute__((ext_vector_type(8)));
typedef float f32x4 __attribute__((ext_vector_type(4)));

#define DIM     1024
#define NEXP    8
#define VOCAB   16384
#define HIDDEN  2730
#define UPOUT   5460
#define NTOK    2048
#define NSLOT   4096
#define HRAW_LD 5472
#define H1_LD   2752
#define BM      256
#define MAXTILES 24

// ws layout (offsets in bytes)
#define WS_COUNTS      0
#define WS_NTILES      64
#define WS_TILE_E      128
#define WS_TILE_M0     384
#define WS_TILE_MEND   640
#define WS_SLOT_IDS    1024
#define WS_SLOT_W      17408
#define WS_SLOT_OF_POS 33792
#define WS_POS_OF_SLOT 50176
#define WS_XSORTED     66560
#define WS_H2          8455168
#define WS_H1          16843776
#define WS_HRAW        39388160
#define WS_LOGITS      16843776ull              /* overlays h1+h_raw (dead by proj) */
#define WS_NEED_BIG    (WS_LOGITS + (size_t)NSLOT * VOCAB * 2)

__device__ __forceinline__ void gload_lds16(const void* g, void* l) {
    __builtin_amdgcn_global_load_lds((const __attribute__((address_space(1))) void*)g,
                                     (__attribute__((address_space(3))) void*)l, 16, 0, 0);
}
__device__ __forceinline__ int swzm(int r) { return (r ^ (r >> 2)) & 3; }

// ---------------- router ----------------
__global__ __launch_bounds__(256) void router_kernel(const float* __restrict__ x,
        const float* __restrict__ wr, int* __restrict__ slot_ids,
        float* __restrict__ slot_w, int* __restrict__ counts) {
    const int lane = threadIdx.x & 63;
    const int wave = threadIdx.x >> 6;
    const int token = blockIdx.x * 4 + wave;
    const float* xrow = x + (size_t)token * DIM;
    float acc[NEXP];
#pragma unroll
    for (int e = 0; e < NEXP; ++e) acc[e] = 0.f;
#pragma unroll
    for (int i = 0; i < DIM / 64; ++i) {
        const int k = i * 64 + lane;
        const float xv = xrow[k];
#pragma unroll
        for (int e = 0; e < NEXP; ++e) acc[e] += xv * wr[e * DIM + k];
    }
#pragma unroll
    for (int off = 32; off > 0; off >>= 1) {
#pragma unroll
        for (int e = 0; e < NEXP; ++e) acc[e] += __shfl_xor(acc[e], off);
    }
    if (lane == 0) {
        float c0 = -1e30f; int b0 = 0;
#pragma unroll
        for (int e = 0; e < NEXP; ++e) if (acc[e] > c0) { c0 = acc[e]; b0 = e; }
        float c1 = -1e30f; int b1 = 0;
#pragma unroll
        for (int e = 0; e < NEXP; ++e) if (e != b0 && acc[e] > c1) { c1 = acc[e]; b1 = e; }
        slot_ids[token * 2 + 0] = b0;
        slot_ids[token * 2 + 1] = b1;
        const float w0 = 1.f / (1.f + expf(c1 - c0));
        slot_w[token * 2 + 0] = w0;
        slot_w[token * 2 + 1] = 1.f - w0;
        atomicAdd(&counts[b0], 1);
        atomicAdd(&counts[b1], 1);
    }
}

// ---------------- scheduler ----------------
__global__ __launch_bounds__(512) void sched_kernel(const int* __restrict__ counts,
        int* __restrict__ ntiles, int* __restrict__ tile_e, int* __restrict__ tile_m0,
        int* __restrict__ tile_mend, const int* __restrict__ slot_ids,
        int* __restrict__ slot_of_pos, int* __restrict__ pos_of_slot) {
    __shared__ int offs[NEXP];
    if (threadIdx.x == 0) {
        int o = 0, nt = 0;
        for (int e = 0; e < NEXP; ++e) {
            offs[e] = o;
            const int c = counts[e];
            for (int m = 0; m < c; m += BM) {
                tile_e[nt] = e; tile_m0[nt] = o + m; tile_mend[nt] = o + c; ++nt;
            }
            o += c;
        }
        *ntiles = nt;
    }
    __syncthreads();
    const int e = threadIdx.x >> 6;
    const int lane = threadIdx.x & 63;
    int base = offs[e];
    for (int ch = 0; ch < NSLOT / 64; ++ch) {
        const int i = ch * 64 + lane;
        const int id = slot_ids[i];
        const unsigned long long m = __ballot(id == e);
        if (id == e) {
            const int rank = __popcll(m & ((1ull << lane) - 1ull));
            slot_of_pos[base + rank] = i;
            pos_of_slot[i] = base + rank;
        }
        base += __popcll(m);
    }
}

// ---------------- gather ----------------
__global__ __launch_bounds__(256) void gather_kernel(const float* __restrict__ x,
        const int* __restrict__ slot_of_pos, bf16_t* __restrict__ xs) {
    const int row = blockIdx.x;
    const int t = threadIdx.x;
    const int tok = slot_of_pos[row] >> 1;
    const float4 v = *(const float4*)(x + (size_t)tok * DIM + t * 4);
    bf16x4 o;
    o.x = (bf16_t)v.x; o.y = (bf16_t)v.y; o.z = (bf16_t)v.z; o.w = (bf16_t)v.w;
    *(bf16x4*)(xs + (size_t)row * DIM + t * 4) = o;
}

// ---------------- swiglu ----------------
__global__ __launch_bounds__(256) void swiglu_kernel(const bf16_t* __restrict__ hraw,
        bf16_t* __restrict__ h1) {
    const int row = blockIdx.x;
    const int col = blockIdx.y * 256 + threadIdx.x;
    if (col >= H1_LD) return;
    float o = 0.f;
    if (col < HIDDEN) {
        const float a = (float)hraw[(size_t)row * HRAW_LD + col];
        const float g = (float)hraw[(size_t)row * HRAW_LD + col + HIDDEN];
        o = a * (g / (1.f + expf(-g)));
    }
    h1[(size_t)row * H1_LD + col] = (bf16_t)o;
}

// ---------------- combine ----------------
__global__ __launch_bounds__(256) void combine_kernel(const bf16_t* __restrict__ logits,
        const int* __restrict__ pos_of_slot, const float* __restrict__ slot_w,
        float* __restrict__ out) {
    const int t = blockIdx.x;
    const int v0 = (blockIdx.y * 256 + threadIdx.x) * 8;
    const int p0 = pos_of_slot[2 * t], p1 = pos_of_slot[2 * t + 1];
    const float w0 = slot_w[2 * t], w1 = slot_w[2 * t + 1];
    const bf16x8 a = *(const bf16x8*)(logits + (size_t)p0 * VOCAB + v0);
    const bf16x8 b = *(const bf16x8*)(logits + (size_t)p1 * VOCAB + v0);
    float o[8];
#pragma unroll
    for (int i = 0; i < 8; ++i) o[i] = w0 * (float)a[i] + w1 * (float)b[i];
    *(float4*)(out + (size_t)t * VOCAB + v0)     = make_float4(o[0], o[1], o[2], o[3]);
    *(float4*)(out + (size_t)t * VOCAB + v0 + 4) = make_float4(o[4], o[5], o[6], o[7]);
}

// ================= gemm_big: BM=256 BN=256 BK=64, K=1024, 8 waves (2Mx4N) =================
// 4 phases per K-tile; counted vmcnt at phases 3/4 only; A via global_load_lds(16B),
// B fp32 reg-staged (load ph1-2, cvt+ds_write ph3-4). LDS unit-swizzle u ^= (row&7).
// EPI 0: store bf16 C[ldc]   2: scaled atomicAdd into out   3: store bf16 logits[VOCAB]
template <int EPI>
__global__ __launch_bounds__(512, 2) void gemm_big(
        const bf16_t* __restrict__ A,
        const float* __restrict__ B, int N,
        bf16_t* __restrict__ C, int ldc,
        const int* __restrict__ slot_of_pos,
        const float* __restrict__ slot_w,
        float* __restrict__ outp,
        const int* __restrict__ tile_e,
        const int* __restrict__ tile_m0,
        const int* __restrict__ tile_mend,
        const int* __restrict__ ntiles) {
    if (blockIdx.y >= (unsigned)*ntiles) return;
    constexpr int K = 1024, KT = 16;
    const int e = tile_e[blockIdx.y];
    const int m0 = tile_m0[blockIdx.y];
    const int mend = tile_mend[blockIdx.y];
    const int n0 = blockIdx.x * 256;

    __shared__ bf16_t sA[2][256][64];   // 64 KB: LDS[r][u] = G[r][u ^ (r&7)] (16B units)
    __shared__ bf16_t sB[2][256][64];   // 64 KB

    const int tid = threadIdx.x;
    const int lane = tid & 63;
    const int wave = tid >> 6;
    const int wr = wave >> 2;            // 0..1 -> M strip wr*128
    const int wc = wave & 3;             // 0..3 -> N strip wc*64
    const int fr = lane & 15;
    const int fq = lane >> 4;

    // B staging: thread -> (row = tid>>1, k-half = tid&1): 8 f32x4 loads, 4 b128 writes
    const int brow = tid >> 1;
    const int bhalf = tid & 1;
    const int bswz = brow & 7;
    const float* bsrc = B + (size_t)e * N * K + (size_t)min(n0 + brow, N - 1) * K
                          + bhalf * 32;

    f32x4 acc[8][4] = {};
    bf16x8 af[4][2], bb[4][2];
    f32x4 l[8];

    auto dmaA = [&](int buf, int t, int j) {
        const int k0 = min(t, KT - 1) * 64;
        const int rb = j * 64 + wave * 8;
        const int r  = rb + (lane >> 3);
        const int gr = min(m0 + r, NSLOT - 1);
        const int su = (lane & 7) ^ (r & 7);     // pre-swizzled source unit
        gload_lds16(A + (size_t)gr * K + k0 + su * 8, &sA[buf][rb][0]);
    };
    auto loadB4 = [&](int t, int base) {
        const int k0 = min(t, KT - 1) * 64;
#pragma unroll
        for (int j = 0; j < 4; ++j)
            l[base + j] = *(const f32x4*)(bsrc + k0 + (base + j) * 4);
    };
    auto writeB = [&](int buf, int w) {
        bf16x8 t;
        t[0] = (bf16_t)l[2*w][0]; t[1] = (bf16_t)l[2*w][1];
        t[2] = (bf16_t)l[2*w][2]; t[3] = (bf16_t)l[2*w][3];
        t[4] = (bf16_t)l[2*w+1][0]; t[5] = (bf16_t)l[2*w+1][1];
        t[6] = (bf16_t)l[2*w+1][2]; t[7] = (bf16_t)l[2*w+1][3];
        const int us = (bhalf * 4 + w) ^ bswz;
        *(bf16x8*)&sB[buf][brow][us * 8] = t;
    };
    auto readA = [&](int buf, int mh) {
#pragma unroll
        for (int kk = 0; kk < 2; ++kk)
#pragma unroll
            for (int mi = 0; mi < 4; ++mi) {
                const int r = wr * 128 + mh * 64 + mi * 16 + fr;
                af[mi][kk] = *(const bf16x8*)&sA[buf][r][((kk * 4 + fq) ^ (r & 7)) * 8];
            }
    };
    auto readB = [&](int buf, int nh) {
#pragma unroll
        for (int kk = 0; kk < 2; ++kk)
#pragma unroll
            for (int ni = 0; ni < 2; ++ni) {
                const int r = wc * 64 + nh * 32 + ni * 16 + fr;
                bb[nh * 2 + ni][kk] =
                    *(const bf16x8*)&sB[buf][r][((kk * 4 + fq) ^ (r & 7)) * 8];
            }
    };
    auto quad = [&](int mh, int nh) {       // 16 MFMA, one C-quadrant x K=64
        __builtin_amdgcn_s_setprio(1);
#pragma unroll
        for (int kk = 0; kk < 2; ++kk)
#pragma unroll
            for (int ni = 0; ni < 2; ++ni)
#pragma unroll
                for (int mi = 0; mi < 4; ++mi)
                    acc[mh * 4 + mi][nh * 2 + ni] =
                        __builtin_amdgcn_mfma_f32_16x16x32_bf16(
                            af[mi][kk], bb[nh * 2 + ni][kk],
                            acc[mh * 4 + mi][nh * 2 + ni], 0, 0, 0);
        __builtin_amdgcn_s_setprio(0);
    };

    // ---- prologue: stage tile 0 into buf 0
    loadB4(0, 0); loadB4(0, 4);
#pragma unroll
    for (int j = 0; j < 4; ++j) dmaA(0, 0, j);
    writeB(0, 0); writeB(0, 1); writeB(0, 2); writeB(0, 3);
    asm volatile("s_waitcnt vmcnt(0)" ::: "memory");
    asm volatile("s_waitcnt lgkmcnt(0)" ::: "memory");
    __builtin_amdgcn_s_barrier();
    asm volatile("" ::: "memory");

    for (int t = 0; t < KT; ++t) {
        const int cur = t & 1;
        // ---- phase 1: quad(0,0); issue B-loads 0-3 + all A-DMA for t+1
        readA(cur, 0); readB(cur, 0);
        loadB4(t + 1, 0);
#pragma unroll
        for (int j = 0; j < 4; ++j) dmaA(cur ^ 1, t + 1, j);
        asm volatile("" ::: "memory");
        __builtin_amdgcn_s_barrier();
        asm volatile("s_waitcnt lgkmcnt(0)" ::: "memory");
        __builtin_amdgcn_sched_barrier(0);
        quad(0, 0);
        asm volatile("" ::: "memory");
        __builtin_amdgcn_s_barrier();
        // ---- phase 2: quad(0,1); issue B-loads 4-7
        readB(cur, 1);
        loadB4(t + 1, 4);
        asm volatile("" ::: "memory");
        __builtin_amdgcn_s_barrier();
        asm volatile("s_waitcnt lgkmcnt(0)" ::: "memory");
        __builtin_amdgcn_sched_barrier(0);
        quad(0, 1);
        asm volatile("" ::: "memory");
        __builtin_amdgcn_s_barrier();
        // ---- phase 3: quad(1,0); drain B-loads 0-3 (counted), cvt+write
        asm volatile("s_waitcnt vmcnt(8)" ::: "memory");
        writeB(cur ^ 1, 0); writeB(cur ^ 1, 1);
        readA(cur, 1);
        asm volatile("" ::: "memory");
        __builtin_amdgcn_s_barrier();
        asm volatile("s_waitcnt lgkmcnt(0)" ::: "memory");
        __builtin_amdgcn_sched_barrier(0);
        quad(1, 0);
        asm volatile("" ::: "memory");
        __builtin_amdgcn_s_barrier();
        // ---- phase 4: quad(1,1); drain rest (B 4-7 + A-DMA), cvt+write
        asm volatile("s_waitcnt vmcnt(0)" ::: "memory");
        writeB(cur ^ 1, 2); writeB(cur ^ 1, 3);
        asm volatile("" ::: "memory");
        __builtin_amdgcn_s_barrier();
        asm volatile("s_waitcnt lgkmcnt(0)" ::: "memory");
        __builtin_amdgcn_sched_barrier(0);
        quad(1, 1);
        asm volatile("" ::: "memory");
        __builtin_amdgcn_s_barrier();
    }

    // ---- epilogue: C/D layout col = lane&15, row = (lane>>4)*4 + reg
#pragma unroll
    for (int a = 0; a < 8; ++a) {
#pragma unroll
        for (int reg = 0; reg < 4; ++reg) {
            const int r = m0 + wr * 128 + (a >> 2) * 64 + (a & 3) * 16 + fq * 4 + reg;
            if (r >= mend) continue;
            int tok = 0; float wgt = 0.f;
            if constexpr (EPI == 2) {
                const int slot = slot_of_pos[r];
                tok = slot >> 1;
                wgt = slot_w[slot];
            }
#pragma unroll
            for (int b = 0; b < 4; ++b) {
                const int c = n0 + wc * 64 + (b >> 1) * 32 + (b & 1) * 16 + fr;
                if (c >= N) continue;
                float v = acc[a][b][reg];
                if constexpr (EPI == 0) {
                    C[(size_t)r * ldc + c] = (bf16_t)v;
                } else if constexpr (EPI == 2) {
                    unsafeAtomicAdd(&outp[(size_t)tok * VOCAB + c], v * wgt);
                } else {
                    C[(size_t)r * VOCAB + c] = (bf16_t)v;
                }
            }
        }
    }
}

// ================= gemm_mid (R5 structure, kept for down-GEMM K=2730, BN=64) ============
template <int EPI, bool BW16, int BN, bool SWZ>
__global__ __launch_bounds__(1024, 4) void gemm_mid(
        const bf16_t* __restrict__ A, int lda,
        const float* __restrict__ B, int N, int K, int KT, long bLast,
        bf16_t* __restrict__ C, int ldc,
        const bf16_t* __restrict__ skip,
        const int* __restrict__ slot_of_pos,
        const float* __restrict__ slot_w,
        float* __restrict__ outp,
        const int* __restrict__ tile_e,
        const int* __restrict__ tile_m0,
        const int* __restrict__ tile_mend,
        const int* __restrict__ ntiles) {
    if (blockIdx.y >= (unsigned)*ntiles) return;
    int bx = blockIdx.x;
    if constexpr (SWZ) bx = (bx & 7) * (gridDim.x >> 3) + (bx >> 3);
    const int e = tile_e[blockIdx.y];
    const int m0 = tile_m0[blockIdx.y];
    const int mend = tile_mend[blockIdx.y];
    const int n0 = bx * BN;

    constexpr int NI = BN / 64;

    __shared__ bf16_t sA[2][BM][32];
    __shared__ bf16_t sB[2][BN][32];

    const int tid = threadIdx.x;
    const int lane = tid & 63;
    const int wave = tid >> 6;
    const int wr = wave >> 2;
    const int wc = wave & 3;
    const int fr = lane & 15;
    const int fq = lane >> 4;

    f32x4 acc[4][NI] = {};

    auto stageA = [&](int buf, int kt) {
        const int k0 = min(kt, KT - 1) * 32;
        const int rb = wave * 16;
        const int r = rb + (lane >> 2);
        const int gr = min(m0 + r, NSLOT - 1);
        const int c16 = (lane & 3) ^ swzm(r);
        gload_lds16(A + (size_t)gr * lda + k0 + c16 * 8, &sA[buf][rb][0]);
    };
    auto loadB = [&](int kt, f32x4& va, float2& vc) {
        const int k0 = min(kt, KT - 1) * 32;
        if constexpr (BW16) {
            va = *(const f32x4*)(B + (size_t)e * N * K
                 + (size_t)min(n0 + wave * 8 + (lane >> 3), N - 1) * K + k0 + (lane & 7) * 4);
        } else {
            long fl = (long)e * N * K + (long)(n0 + wave * 4 + (lane >> 4)) * K
                      + k0 + (lane & 15) * 2;
            if (fl > bLast) fl = bLast;
            vc = *(const float2*)(B + fl);
        }
    };
    auto writeB = [&](int buf, const f32x4& va, const float2& vc) {
        if constexpr (BW16) {
            const int r = wave * 8 + (lane >> 3);
            bf16x4 t;
            t.x = (bf16_t)va.x; t.y = (bf16_t)va.y;
            t.z = (bf16_t)va.z; t.w = (bf16_t)va.w;
            char* p = (char*)&sB[buf][r][0]
                    + ((((lane & 7) >> 1) ^ swzm(r)) * 16) + (lane & 1) * 8;
            *(bf16x4*)p = t;
        } else {
            const int r = wave * 4 + (lane >> 4);
            bf16x2 t; t.x = (bf16_t)vc.x; t.y = (bf16_t)vc.y;
            const int q = lane & 15;
            char* p = (char*)&sB[buf][r][0] + (((q >> 2) ^ swzm(r)) * 16) + (q & 3) * 4;
            *(bf16x2*)p = t;
        }
    };
    auto compute = [&](int buf) {
        bf16x8 af[4], bb[NI];
#pragma unroll
        for (int mi = 0; mi < 4; ++mi) {
            const int r = wr * 64 + mi * 16 + fr;
            af[mi] = *(const bf16x8*)&sA[buf][r][(fq ^ swzm(r)) * 8];
        }
#pragma unroll
        for (int ni = 0; ni < NI; ++ni) {
            const int r = wc * (BN / 4) + ni * 16 + fr;
            bb[ni] = *(const bf16x8*)&sB[buf][r][(fq ^ swzm(r)) * 8];
        }
        __builtin_amdgcn_s_setprio(1);
#pragma unroll
        for (int ni = 0; ni < NI; ++ni)
#pragma unroll
            for (int mi = 0; mi < 4; ++mi)
                acc[mi][ni] = __builtin_amdgcn_mfma_f32_16x16x32_bf16(
                        af[mi], bb[ni], acc[mi][ni], 0, 0, 0);
        __builtin_amdgcn_s_setprio(0);
    };

    f32x4 Pa, Qa; float2 Pc, Qc;
    loadB(0, Pa, Pc);
    stageA(0, 0);
    loadB(1, Qa, Qc);
    asm volatile("s_waitcnt vmcnt(2)" ::: "memory");
    writeB(0, Pa, Pc);
    asm volatile("s_waitcnt lgkmcnt(0)" ::: "memory");
    stageA(1, 1);

    for (int kt = 0; kt < KT; kt += 2) {
        loadB(kt + 2, Pa, Pc);
        asm volatile("s_waitcnt vmcnt(2)" ::: "memory");
        __builtin_amdgcn_s_barrier();
        asm volatile("" ::: "memory");
        writeB(1, Qa, Qc);
        compute(0);
        asm volatile("s_waitcnt lgkmcnt(0)" ::: "memory");
        __builtin_amdgcn_s_barrier();
        asm volatile("" ::: "memory");
        stageA(0, kt + 2);
        loadB(kt + 3, Qa, Qc);
        asm volatile("s_waitcnt vmcnt(2)" ::: "memory");
        __builtin_amdgcn_s_barrier();
        asm volatile("" ::: "memory");
        writeB(0, Pa, Pc);
        compute(1);
        asm volatile("s_waitcnt lgkmcnt(0)" ::: "memory");
        __builtin_amdgcn_s_barrier();
        asm volatile("" ::: "memory");
        stageA(1, kt + 3);
    }

#pragma unroll
    for (int mi = 0; mi < 4; ++mi) {
#pragma unroll
        for (int reg = 0; reg < 4; ++reg) {
            const int r = m0 + wr * 64 + mi * 16 + fq * 4 + reg;
            if (r >= mend) continue;
#pragma unroll
            for (int ni = 0; ni < NI; ++ni) {
                const int c = n0 + wc * (BN / 4) + ni * 16 + fr;
                if (c >= N) continue;
                float v = acc[mi][ni][reg];
                if constexpr (EPI == 1) {
                    v += (float)skip[(size_t)r * DIM + c];
                    C[(size_t)r * ldc + c] = (bf16_t)v;
                } else {
                    C[(size_t)r * ldc + c] = (bf16_t)v;
                }
            }
        }
    }
}

extern "C" void kernel_launch(void* const* d_in, const int* in_sizes, int n_in,
                              void* d_out, int out_size, void* d_ws, size_t ws_size,
                              hipStream_t stream) {
    const float* x        = (const float*)d_in[0];
    const float* w_router = (const float*)d_in[1];
    const float* w_up     = (const float*)d_in[2];
    const float* w_down   = (const float*)d_in[3];
    const float* w_proj   = (const float*)d_in[4];
    float* out = (float*)d_out;
    char* ws = (char*)d_ws;

    int*    counts      = (int*)(ws + WS_COUNTS);
    int*    ntiles      = (int*)(ws + WS_NTILES);
    int*    tile_e      = (int*)(ws + WS_TILE_E);
    int*    tile_m0     = (int*)(ws + WS_TILE_M0);
    int*    tile_mend   = (int*)(ws + WS_TILE_MEND);
    int*    slot_ids    = (int*)(ws + WS_SLOT_IDS);
    float*  slot_w      = (float*)(ws + WS_SLOT_W);
    int*    slot_of_pos = (int*)(ws + WS_SLOT_OF_POS);
    int*    pos_of_slot = (int*)(ws + WS_POS_OF_SLOT);
    bf16_t* x_sorted    = (bf16_t*)(ws + WS_XSORTED);
    bf16_t* h2          = (bf16_t*)(ws + WS_H2);
    bf16_t* h1          = (bf16_t*)(ws + WS_H1);
    bf16_t* h_raw       = (bf16_t*)(ws + WS_HRAW);
    bf16_t* logits      = (bf16_t*)(ws + WS_LOGITS);

    const bool bigws = ws_size >= WS_NEED_BIG;

    hipMemsetAsync(d_ws, 0, 1024, stream);

    router_kernel<<<NTOK / 4, 256, 0, stream>>>(x, w_router, slot_ids, slot_w, counts);
    sched_kernel<<<1, 512, 0, stream>>>(counts, ntiles, tile_e, tile_m0, tile_mend,
                                        slot_ids, slot_of_pos, pos_of_slot);
    gather_kernel<<<NSLOT, 256, 0, stream>>>(x, slot_of_pos, x_sorted);

    gemm_big<0><<<dim3((UPOUT + 255) / 256, MAXTILES), 512, 0, stream>>>(
        x_sorted, w_up, UPOUT, h_raw, HRAW_LD,
        nullptr, nullptr, nullptr, tile_e, tile_m0, tile_mend, ntiles);

    swiglu_kernel<<<dim3(NSLOT, (H1_LD + 255) / 256), 256, 0, stream>>>(h_raw, h1);

    gemm_mid<1, false, 64, true><<<dim3(DIM / 64, MAXTILES), 1024, 0, stream>>>(
        h1, H1_LD, w_down, DIM, HIDDEN, (HIDDEN + 31) / 32,
        (long)NEXP * DIM * HIDDEN - 2,
        h2, DIM,
        x_sorted, nullptr, nullptr, nullptr, tile_e, tile_m0, tile_mend, ntiles);

    if (bigws) {
        gemm_big<3><<<dim3(VOCAB / 256, MAXTILES), 512, 0, stream>>>(
            h2, w_proj, VOCAB, logits, VOCAB,
            nullptr, nullptr, nullptr, tile_e, tile_m0, tile_mend, ntiles);
        combine_kernel<<<dim3(NTOK, VOCAB / (256 * 8)), 256, 0, stream>>>(
            logits, pos_of_slot, slot_w, out);
    } else {
        hipMemsetAsync(d_out, 0, (size_t)out_size * sizeof(float), stream);
        gemm_big<2><<<dim3(VOCAB / 256, MAXTILES), 512, 0, stream>>>(
            h2, w_proj, VOCAB, nullptr, 0,
            slot_of_pos, slot_w, out, tile_e, tile_m0, tile_mend, ntiles);
    }
}

// Round 8
// 631.428 us; speedup vs baseline: 1.2436x; 1.2436x over previous
//
#include <hip/hip_runtime.h>
#include <hip/hip_bf16.h>

typedef __bf16 bf16_t;
typedef __bf16 bf16x2 __attribute__((ext_vector_type(2)));
typedef __bf16 bf16x4 __attribute__((ext_vector_type(4)));
typedef __bf16 bf16x8 __attribute__((ext_vector_type(8)));
typedef float f32x4 __attribute__((ext_vector_type(4)));

#define DIM     1024
#define NEXP    8
#define VOCAB   16384
#define HIDDEN  2730
#define UPOUT   5460
#define NTOK    2048
#define NSLOT   4096
#define HRAW_LD 5472
#define H1_LD   2752
#define BM      256
#define MAXTILES 24

// ws layout (offsets in bytes) — each array has verified slack:
// counts 64B@0 | ntiles 4B@64 | tile_e 128B@128 | tile_m0 128B@256 | tile_mend 128B@384
// (ntiles <= 8 + 4096/256 = 24 entries = 96 B < 128 B each)
#define WS_COUNTS      0
#define WS_NTILES      64
#define WS_TILE_E      128
#define WS_TILE_M0     256
#define WS_TILE_MEND   384
#define WS_SLOT_IDS    1024        /* 16 KB */
#define WS_SLOT_W      20480       /* 16 KB */
#define WS_SLOT_OF_POS 40960       /* 16 KB */
#define WS_POS_OF_SLOT 61440       /* 16 KB */
#define WS_XSORTED     131072      /* 8 MB  -> end   8519680 */
#define WS_H2          8519680     /* 8 MB  -> end  16908288 */
#define WS_H1          16908288    /* 22 MB -> end  39452672 */
#define WS_HRAW        39452672    /* 45 MB -> end  84279296 */
#define WS_LOGITS      16908288ull /* overlays h1+h_raw (dead by proj time) */
#define WS_NEED_BIG    (WS_LOGITS + (size_t)NSLOT * VOCAB * 2)   /* 151,126,016 */

__device__ __forceinline__ void gload_lds16(const void* g, void* l) {
    __builtin_amdgcn_global_load_lds((const __attribute__((address_space(1))) void*)g,
                                     (__attribute__((address_space(3))) void*)l, 16, 0, 0);
}
__device__ __forceinline__ int swzm(int r) { return (r ^ (r >> 2)) & 3; }

// ---------------- router ----------------
__global__ __launch_bounds__(256) void router_kernel(const float* __restrict__ x,
        const float* __restrict__ wr, int* __restrict__ slot_ids,
        float* __restrict__ slot_w, int* __restrict__ counts) {
    const int lane = threadIdx.x & 63;
    const int wave = threadIdx.x >> 6;
    const int token = blockIdx.x * 4 + wave;
    const float* xrow = x + (size_t)token * DIM;
    float acc[NEXP];
#pragma unroll
    for (int e = 0; e < NEXP; ++e) acc[e] = 0.f;
#pragma unroll
    for (int i = 0; i < DIM / 64; ++i) {
        const int k = i * 64 + lane;
        const float xv = xrow[k];
#pragma unroll
        for (int e = 0; e < NEXP; ++e) acc[e] += xv * wr[e * DIM + k];
    }
#pragma unroll
    for (int off = 32; off > 0; off >>= 1) {
#pragma unroll
        for (int e = 0; e < NEXP; ++e) acc[e] += __shfl_xor(acc[e], off);
    }
    if (lane == 0) {
        float c0 = -1e30f; int b0 = 0;
#pragma unroll
        for (int e = 0; e < NEXP; ++e) if (acc[e] > c0) { c0 = acc[e]; b0 = e; }
        float c1 = -1e30f; int b1 = 0;
#pragma unroll
        for (int e = 0; e < NEXP; ++e) if (e != b0 && acc[e] > c1) { c1 = acc[e]; b1 = e; }
        slot_ids[token * 2 + 0] = b0;
        slot_ids[token * 2 + 1] = b1;
        const float w0 = 1.f / (1.f + expf(c1 - c0));
        slot_w[token * 2 + 0] = w0;
        slot_w[token * 2 + 1] = 1.f - w0;
        atomicAdd(&counts[b0], 1);
        atomicAdd(&counts[b1], 1);
    }
}

// ---------------- scheduler: offsets, tile list (BM=256), stable counting-sort ranks ----
__global__ __launch_bounds__(512) void sched_kernel(const int* __restrict__ counts,
        int* __restrict__ ntiles, int* __restrict__ tile_e, int* __restrict__ tile_m0,
        int* __restrict__ tile_mend, const int* __restrict__ slot_ids,
        int* __restrict__ slot_of_pos, int* __restrict__ pos_of_slot) {
    __shared__ int offs[NEXP];
    if (threadIdx.x == 0) {
        int o = 0, nt = 0;
        for (int e = 0; e < NEXP; ++e) {
            offs[e] = o;
            const int c = counts[e];
            for (int m = 0; m < c; m += BM) {
                tile_e[nt] = e; tile_m0[nt] = o + m; tile_mend[nt] = o + c; ++nt;
            }
            o += c;
        }
        *ntiles = nt;
    }
    __syncthreads();
    const int e = threadIdx.x >> 6;
    const int lane = threadIdx.x & 63;
    int base = offs[e];
    for (int ch = 0; ch < NSLOT / 64; ++ch) {
        const int i = ch * 64 + lane;
        const int id = slot_ids[i];
        const unsigned long long m = __ballot(id == e);
        if (id == e) {
            const int rank = __popcll(m & ((1ull << lane) - 1ull));
            slot_of_pos[base + rank] = i;
            pos_of_slot[i] = base + rank;
        }
        base += __popcll(m);
    }
}

// ---------------- gather ----------------
__global__ __launch_bounds__(256) void gather_kernel(const float* __restrict__ x,
        const int* __restrict__ slot_of_pos, bf16_t* __restrict__ xs) {
    const int row = blockIdx.x;
    const int t = threadIdx.x;
    const int tok = slot_of_pos[row] >> 1;
    const float4 v = *(const float4*)(x + (size_t)tok * DIM + t * 4);
    bf16x4 o;
    o.x = (bf16_t)v.x; o.y = (bf16_t)v.y; o.z = (bf16_t)v.z; o.w = (bf16_t)v.w;
    *(bf16x4*)(xs + (size_t)row * DIM + t * 4) = o;
}

// ---------------- swiglu ----------------
__global__ __launch_bounds__(256) void swiglu_kernel(const bf16_t* __restrict__ hraw,
        bf16_t* __restrict__ h1) {
    const int row = blockIdx.x;
    const int col = blockIdx.y * 256 + threadIdx.x;
    if (col >= H1_LD) return;
    float o = 0.f;
    if (col < HIDDEN) {
        const float a = (float)hraw[(size_t)row * HRAW_LD + col];
        const float g = (float)hraw[(size_t)row * HRAW_LD + col + HIDDEN];
        o = a * (g / (1.f + expf(-g)));
    }
    h1[(size_t)row * H1_LD + col] = (bf16_t)o;
}

// ---------------- combine ----------------
__global__ __launch_bounds__(256) void combine_kernel(const bf16_t* __restrict__ logits,
        const int* __restrict__ pos_of_slot, const float* __restrict__ slot_w,
        float* __restrict__ out) {
    const int t = blockIdx.x;
    const int v0 = (blockIdx.y * 256 + threadIdx.x) * 8;
    const int p0 = pos_of_slot[2 * t], p1 = pos_of_slot[2 * t + 1];
    const float w0 = slot_w[2 * t], w1 = slot_w[2 * t + 1];
    const bf16x8 a = *(const bf16x8*)(logits + (size_t)p0 * VOCAB + v0);
    const bf16x8 b = *(const bf16x8*)(logits + (size_t)p1 * VOCAB + v0);
    float o[8];
#pragma unroll
    for (int i = 0; i < 8; ++i) o[i] = w0 * (float)a[i] + w1 * (float)b[i];
    *(float4*)(out + (size_t)t * VOCAB + v0)     = make_float4(o[0], o[1], o[2], o[3]);
    *(float4*)(out + (size_t)t * VOCAB + v0 + 4) = make_float4(o[4], o[5], o[6], o[7]);
}

// ---------------- grouped GEMM: C[m,n] = sum_k A[m,k] * W[n,k]
// BM=256 x BN (256/128/64), BK=32, 1024 threads = 16 waves (4M x 4N), per-wave 64 x BN/4.
// R5's never-drain P/Q pipeline; loads/wave/step = NB(B) + 1(A-DMA); vmcnt(NB+1).
// A (bf16, L2-resident) via global_load_lds(16B) pre-swizzled source;
// B (fp32 HBM stream) reg-staged f32x4 -> cvt bf16 -> swizzled ds_write.
// EPI 0: store bf16  1: +skip, store bf16  2: scaled atomicAdd  (logits use EPI 0)
template <int EPI, bool BW16, int BN, bool SWZ>
__global__ __launch_bounds__(1024, 4) void gemm_kernel(
        const bf16_t* __restrict__ A, int lda,
        const float* __restrict__ B, int N, int K, int KT, long bLast,
        bf16_t* __restrict__ C, int ldc,
        const bf16_t* __restrict__ skip,
        const int* __restrict__ slot_of_pos,
        const float* __restrict__ slot_w,
        float* __restrict__ outp,
        const int* __restrict__ tile_e,
        const int* __restrict__ tile_m0,
        const int* __restrict__ tile_mend,
        const int* __restrict__ ntiles) {
    if (blockIdx.y >= (unsigned)*ntiles) return;
    int bx = blockIdx.x;
    if constexpr (SWZ) bx = (bx & 7) * (gridDim.x >> 3) + (bx >> 3);
    const int e = tile_e[blockIdx.y];
    const int m0 = tile_m0[blockIdx.y];
    const int mend = tile_mend[blockIdx.y];
    const int n0 = bx * BN;

    constexpr int NI = BN / 64;               // acc frags in N (1,2,4)
    constexpr int NB = BW16 ? BN / 128 : 1;   // B-load instructions per step (1 or 2)
    constexpr int VM = NB + 1;                // counted vmcnt

    __shared__ bf16_t sA[2][BM][32];          // 16 KB/buf, unit16 ^= swzm(row)
    __shared__ bf16_t sB[2][BN][32];          // BN*64 B/buf

    const int tid = threadIdx.x;
    const int lane = tid & 63;
    const int wave = tid >> 6;
    const int wr = wave >> 2;                 // 0..3 -> M strip wr*64
    const int wc = wave & 3;                  // 0..3 -> N strip wc*(BN/4)
    const int fr = lane & 15;
    const int fq = lane >> 4;

    f32x4 acc[4][NI] = {};

    auto stageA = [&](int buf, int kt) {      // 1 x 1KB DMA per wave
        const int k0 = min(kt, KT - 1) * 32;
        const int rb = wave * 16;
        const int r = rb + (lane >> 2);
        const int gr = min(m0 + r, NSLOT - 1);
        const int c16 = (lane & 3) ^ swzm(r); // pre-swizzled source, linear dest
        gload_lds16(A + (size_t)gr * lda + k0 + c16 * 8, &sA[buf][rb][0]);
    };
    auto loadB = [&](int kt, f32x4* va, float2& vc) {
        const int k0 = min(kt, KT - 1) * 32;
        if constexpr (BW16) {                 // NB x (128 rows, 32 k-cols)
#pragma unroll
            for (int nb = 0; nb < NB; ++nb) {
                const int gr = min(n0 + nb * 128 + wave * 8 + (lane >> 3), N - 1);
                va[nb] = *(const f32x4*)(B + (size_t)e * N * K + (size_t)gr * K
                                         + k0 + (lane & 7) * 4);
            }
        } else {                              // 64 rows, 8B-aligned path (K=2730)
            long fl = (long)e * N * K + (long)(n0 + wave * 4 + (lane >> 4)) * K
                      + k0 + (lane & 15) * 2;
            if (fl > bLast) fl = bLast;       // K tail: A is zero there
            vc = *(const float2*)(B + fl);
        }
    };
    auto writeB = [&](int buf, const f32x4* va, const float2& vc) {
        if constexpr (BW16) {
#pragma unroll
            for (int nb = 0; nb < NB; ++nb) {
                const int r = nb * 128 + wave * 8 + (lane >> 3);
                bf16x4 t;
                t.x = (bf16_t)va[nb].x; t.y = (bf16_t)va[nb].y;
                t.z = (bf16_t)va[nb].z; t.w = (bf16_t)va[nb].w;
                char* p = (char*)&sB[buf][r][0]
                        + ((((lane & 7) >> 1) ^ swzm(r)) * 16) + (lane & 1) * 8;
                *(bf16x4*)p = t;
            }
        } else {
            const int r = wave * 4 + (lane >> 4);
            bf16x2 t; t.x = (bf16_t)vc.x; t.y = (bf16_t)vc.y;
            const int q = lane & 15;
            char* p = (char*)&sB[buf][r][0] + (((q >> 2) ^ swzm(r)) * 16) + (q & 3) * 4;
            *(bf16x2*)p = t;
        }
    };
    auto compute = [&](int buf) {
        bf16x8 bb[NI];
#pragma unroll
        for (int ni = 0; ni < NI; ++ni) {
            const int r = wc * (BN / 4) + ni * 16 + fr;
            bb[ni] = *(const bf16x8*)&sB[buf][r][(fq ^ swzm(r)) * 8];
        }
        __builtin_amdgcn_s_setprio(1);
#pragma unroll
        for (int mi = 0; mi < 4; ++mi) {
            const int r = wr * 64 + mi * 16 + fr;
            const bf16x8 af = *(const bf16x8*)&sA[buf][r][(fq ^ swzm(r)) * 8];
#pragma unroll
            for (int ni = 0; ni < NI; ++ni)
                acc[mi][ni] = __builtin_amdgcn_mfma_f32_16x16x32_bf16(
                        af, bb[ni], acc[mi][ni], 0, 0, 0);
        }
        __builtin_amdgcn_s_setprio(0);
    };

    f32x4 Pa[NB], Qa[NB]; float2 Pc, Qc;
    // prologue: queue = [B0(NB), A0, B1(NB)]; vmcnt(VM) leaves {A0,B1} -> B0 in regs
    loadB(0, Pa, Pc);
    stageA(0, 0);
    loadB(1, Qa, Qc);
    asm volatile("s_waitcnt vmcnt(%0)" :: "n"(VM) : "memory");
    writeB(0, Pa, Pc);
    asm volatile("s_waitcnt lgkmcnt(0)" ::: "memory");
    stageA(1, 1);

    for (int kt = 0; kt < KT; kt += 2) {
        // even step: queue = [A(kt), B(kt+1)xNB, A(kt+1), B(kt+2)xNB] = 2NB+2
        // vmcnt(VM=NB+1) drains A(kt) (LDS ready) + B(kt+1) (regs ready)
        loadB(kt + 2, Pa, Pc);
        asm volatile("s_waitcnt vmcnt(%0)" :: "n"(VM) : "memory");
        __builtin_amdgcn_s_barrier();
        asm volatile("" ::: "memory");
        writeB(1, Qa, Qc);
        compute(0);
        asm volatile("s_waitcnt lgkmcnt(0)" ::: "memory");
        __builtin_amdgcn_s_barrier();
        asm volatile("" ::: "memory");
        stageA(0, kt + 2);
        // odd step
        loadB(kt + 3, Qa, Qc);
        asm volatile("s_waitcnt vmcnt(%0)" :: "n"(VM) : "memory");
        __builtin_amdgcn_s_barrier();
        asm volatile("" ::: "memory");
        writeB(0, Pa, Pc);
        compute(1);
        asm volatile("s_waitcnt lgkmcnt(0)" ::: "memory");
        __builtin_amdgcn_s_barrier();
        asm volatile("" ::: "memory");
        stageA(1, kt + 3);
    }

    // epilogue: C/D layout col = lane&15, row = (lane>>4)*4 + reg
#pragma unroll
    for (int mi = 0; mi < 4; ++mi) {
#pragma unroll
        for (int reg = 0; reg < 4; ++reg) {
            const int r = m0 + wr * 64 + mi * 16 + fq * 4 + reg;
            if (r >= mend) continue;
            int tok = 0; float wgt = 0.f;
            if constexpr (EPI == 2) {
                const int slot = slot_of_pos[r];
                tok = slot >> 1;
                wgt = slot_w[slot];
            }
#pragma unroll
            for (int ni = 0; ni < NI; ++ni) {
                const int c = n0 + wc * (BN / 4) + ni * 16 + fr;
                if (c >= N) continue;
                float v = acc[mi][ni][reg];
                if constexpr (EPI == 0) {
                    C[(size_t)r * ldc + c] = (bf16_t)v;
                } else if constexpr (EPI == 1) {
                    v += (float)skip[(size_t)r * DIM + c];
                    C[(size_t)r * ldc + c] = (bf16_t)v;
                } else {
                    unsafeAtomicAdd(&outp[(size_t)tok * VOCAB + c], v * wgt);
                }
            }
        }
    }
}

extern "C" void kernel_launch(void* const* d_in, const int* in_sizes, int n_in,
                              void* d_out, int out_size, void* d_ws, size_t ws_size,
                              hipStream_t stream) {
    const float* x        = (const float*)d_in[0];
    const float* w_router = (const float*)d_in[1];
    const float* w_up     = (const float*)d_in[2];
    const float* w_down   = (const float*)d_in[3];
    const float* w_proj   = (const float*)d_in[4];
    float* out = (float*)d_out;
    char* ws = (char*)d_ws;

    int*    counts      = (int*)(ws + WS_COUNTS);
    int*    ntiles      = (int*)(ws + WS_NTILES);
    int*    tile_e      = (int*)(ws + WS_TILE_E);
    int*    tile_m0     = (int*)(ws + WS_TILE_M0);
    int*    tile_mend   = (int*)(ws + WS_TILE_MEND);
    int*    slot_ids    = (int*)(ws + WS_SLOT_IDS);
    float*  slot_w      = (float*)(ws + WS_SLOT_W);
    int*    slot_of_pos = (int*)(ws + WS_SLOT_OF_POS);
    int*    pos_of_slot = (int*)(ws + WS_POS_OF_SLOT);
    bf16_t* x_sorted    = (bf16_t*)(ws + WS_XSORTED);
    bf16_t* h2          = (bf16_t*)(ws + WS_H2);
    bf16_t* h1          = (bf16_t*)(ws + WS_H1);
    bf16_t* h_raw       = (bf16_t*)(ws + WS_HRAW);
    bf16_t* logits      = (bf16_t*)(ws + WS_LOGITS);

    const bool bigws = ws_size >= WS_NEED_BIG;

    hipMemsetAsync(d_ws, 0, 1024, stream);

    router_kernel<<<NTOK / 4, 256, 0, stream>>>(x, w_router, slot_ids, slot_w, counts);
    sched_kernel<<<1, 512, 0, stream>>>(counts, ntiles, tile_e, tile_m0, tile_mend,
                                        slot_ids, slot_of_pos, pos_of_slot);
    gather_kernel<<<NSLOT, 256, 0, stream>>>(x, slot_of_pos, x_sorted);

    // up: BN=256 (grid.x=22 not /8 -> no swizzle)
    gemm_kernel<0, true, 256, false><<<dim3((UPOUT + 255) / 256, MAXTILES), 1024, 0, stream>>>(
        x_sorted, DIM, w_up, UPOUT, DIM, 32, 0,
        h_raw, HRAW_LD,
        nullptr, nullptr, nullptr, nullptr, tile_e, tile_m0, tile_mend, ntiles);

    swiglu_kernel<<<dim3(NSLOT, (H1_LD + 255) / 256), 256, 0, stream>>>(h_raw, h1);

    // down: K=2730, BN=64, grid.x=16 (/8 ok -> swizzle)
    gemm_kernel<1, false, 64, true><<<dim3(DIM / 64, MAXTILES), 1024, 0, stream>>>(
        h1, H1_LD, w_down, DIM, HIDDEN, (HIDDEN + 31) / 32,
        (long)NEXP * DIM * HIDDEN - 2,
        h2, DIM,
        x_sorted, nullptr, nullptr, nullptr, tile_e, tile_m0, tile_mend, ntiles);

    if (bigws) {
        // proj: BN=256, grid.x=64 (/8 ok -> swizzle), store bf16 logits
        gemm_kernel<0, true, 256, true><<<dim3(VOCAB / 256, MAXTILES), 1024, 0, stream>>>(
            h2, DIM, w_proj, VOCAB, DIM, 32, 0,
            logits, VOCAB,
            nullptr, nullptr, nullptr, nullptr, tile_e, tile_m0, tile_mend, ntiles);
        combine_kernel<<<dim3(NTOK, VOCAB / (256 * 8)), 256, 0, stream>>>(
            logits, pos_of_slot, slot_w, out);
    } else {
        hipMemsetAsync(d_out, 0, (size_t)out_size * sizeof(float), stream);
        gemm_kernel<2, true, 256, true><<<dim3(VOCAB / 256, MAXTILES), 1024, 0, stream>>>(
            h2, DIM, w_proj, VOCAB, DIM, 32, 0,
            nullptr, 0,
            nullptr, slot_of_pos, slot_w, out, tile_e, tile_m0, tile_mend, ntiles);
    }
}